// Round 12
// baseline (473.080 us; speedup 1.0000x reference)
//
#include <hip/hip_runtime.h>
#include <hip/hip_bf16.h>

typedef __hip_bfloat16 bf16;
typedef __attribute__((ext_vector_type(8))) short short8;
typedef __attribute__((ext_vector_type(4))) float floatx4;

// ---- dtype helpers ----
__device__ inline float ldf(const float* p, size_t i) { return p[i]; }
__device__ inline float ldf(const bf16* p, size_t i) { return (float)p[i]; }
__device__ inline void stf(float* p, size_t i, float v) { p[i] = v; }
__device__ inline void stf(bf16* p, size_t i, float v) { p[i] = (bf16)v; }

// ---- async global->LDS 16B copy ----
__device__ inline void async16(const bf16* g, bf16* l) {
    __builtin_amdgcn_global_load_lds(
        (const __attribute__((address_space(1))) void*)g,
        (__attribute__((address_space(3))) void*)l, 16, 0, 0);
}

// ---- 16B vector load of VEC elements -> fp32 lanes ----
__device__ inline void loadvec(const float* __restrict__ p, float* d) {   // VEC=4
    float4 v = *(const float4*)p;
    d[0] = v.x; d[1] = v.y; d[2] = v.z; d[3] = v.w;
}
__device__ inline void loadvec(const bf16* __restrict__ p, float* d) {    // VEC=8
    uint4 u = *(const uint4*)p;
    const unsigned* w = (const unsigned*)&u;
    #pragma unroll
    for (int j = 0; j < 4; ++j) {
        d[2 * j]     = __uint_as_float(w[j] << 16);
        d[2 * j + 1] = __uint_as_float(w[j] & 0xffff0000u);
    }
}
template <int VEC, typename TOut>
__device__ inline void storevec(TOut* __restrict__ p, const float* d) {
    if constexpr (sizeof(TOut) == 4) {
        #pragma unroll
        for (int j = 0; j < VEC; j += 4) {
            float4 v = {d[j], d[j + 1], d[j + 2], d[j + 3]};
            *(float4*)(p + j) = v;
        }
    } else {
        unsigned w[VEC / 2];
        #pragma unroll
        for (int j = 0; j < VEC / 2; ++j) {
            bf16 lo = (bf16)d[2 * j], hi = (bf16)d[2 * j + 1];
            w[j] = ((unsigned)*(unsigned short*)&hi << 16) | (unsigned)*(unsigned short*)&lo;
        }
        if constexpr (VEC == 8) *(uint4*)p = *(uint4*)&w[0];
        else                    *(uint2*)p = *(uint2*)&w[0];
    }
}

// ---------------------------------------------------------------- dtype detect
__global__ void detect_dtype_kernel(const unsigned short* __restrict__ x, int* __restrict__ flag) {
    __shared__ float s[256];
    float m = 0.0f;
    for (int i = threadIdx.x; i < 512; i += 256) {
        unsigned int u = ((unsigned int)x[i]) << 16;
        float v = __uint_as_float(u);
        if (!isnan(v)) m = fmaxf(m, fabsf(v));
    }
    s[threadIdx.x] = m;
    __syncthreads();
    for (int o = 128; o > 0; o >>= 1) {
        if (threadIdx.x < (unsigned)o) s[threadIdx.x] = fmaxf(s[threadIdx.x], s[threadIdx.x + o]);
        __syncthreads();
    }
    if (threadIdx.x == 0) flag[0] = (s[0] > 1e3f) ? 0 : 1;
}

// ---------------------------------------------------------------- fused converts
struct CvtJobs {
    const void* src[14];
    float* dst[14];
    int off[15];
    int cnt;
};
__global__ void cvt_fused_kernel(CvtJobs j, const int* __restrict__ flag) {
    int t = blockIdx.x * 256 + threadIdx.x;
    if (t >= j.off[j.cnt]) return;
    int k = 0;
    while (t >= j.off[k + 1]) ++k;
    int e = t - j.off[k];
    float v = *flag ? (float)((const bf16*)j.src[k])[e] : ((const float*)j.src[k])[e];
    j.dst[k][e] = v;
}

// W[K][N] (raw dtype per flag) -> Wt[N][K] bf16, three jobs fused
struct WtJobs {
    const void* src[3];
    bf16* dst[3];
    int K[3], N[3];
    int off[4];
};
__global__ void wt_fused_kernel(WtJobs j, const int* __restrict__ flag) {
    int t = blockIdx.x * 256 + threadIdx.x;
    if (t >= j.off[3]) return;
    int k_ = 0;
    while (t >= j.off[k_ + 1]) ++k_;
    int e = t - j.off[k_];
    int K = j.K[k_], Nn = j.N[k_];
    int n = e / K, kk = e % K;
    size_t si = (size_t)kk * Nn + n;
    float v = *flag ? (float)((const bf16*)j.src[k_])[si] : ((const float*)j.src[k_])[si];
    j.dst[k_][e] = (bf16)v;
}

// ---------------------------------------------------------------- CSR build
__global__ void zero_int_kernel(int* a, int n) {
    int i = blockIdx.x * blockDim.x + threadIdx.x;
    if (i < n) a[i] = 0;
}

__global__ void hist_kernel(const int* __restrict__ col, int* __restrict__ counts, int E) {
    int e = blockIdx.x * blockDim.x + threadIdx.x;
    if (e < E) atomicAdd(&counts[col[e]], 1);
}

// ---- 3-pass device-wide exclusive scan ----
__global__ void scan_reduce_kernel(const int* __restrict__ counts, int* __restrict__ bs, int n) {
    __shared__ int s[1024];
    int i = blockIdx.x * 1024 + threadIdx.x;
    s[threadIdx.x] = (i < n) ? counts[i] : 0;
    __syncthreads();
    for (int o = 512; o > 0; o >>= 1) {
        if (threadIdx.x < (unsigned)o) s[threadIdx.x] += s[threadIdx.x + o];
        __syncthreads();
    }
    if (threadIdx.x == 0) bs[blockIdx.x] = s[0];
}

__global__ void scan_blocksums_kernel(int* __restrict__ bs, int nb) {
    __shared__ int s[1024];
    int v = (threadIdx.x < (unsigned)nb) ? bs[threadIdx.x] : 0;
    s[threadIdx.x] = v;
    __syncthreads();
    for (int off = 1; off < 1024; off <<= 1) {
        int t = (threadIdx.x >= (unsigned)off) ? s[threadIdx.x - off] : 0;
        __syncthreads();
        s[threadIdx.x] += t;
        __syncthreads();
    }
    if (threadIdx.x < (unsigned)nb) bs[threadIdx.x] = s[threadIdx.x] - v;  // exclusive
}

__global__ void scan_final_kernel(int* __restrict__ counts, const int* __restrict__ bs,
                                  int* __restrict__ offsets, float* __restrict__ dis, int n) {
    __shared__ int s[1024];
    int i = blockIdx.x * 1024 + threadIdx.x;
    int v = (i < n) ? counts[i] : 0;
    if (i < n) { dis[i] = rsqrtf((float)(v + 1)); counts[i] = 0; }
    s[threadIdx.x] = v;
    __syncthreads();
    for (int off = 1; off < 1024; off <<= 1) {
        int t = (threadIdx.x >= (unsigned)off) ? s[threadIdx.x - off] : 0;
        __syncthreads();
        s[threadIdx.x] += t;
        __syncthreads();
    }
    if (i < n) offsets[i + 1] = s[threadIdx.x] + bs[blockIdx.x];
    if (i == 0) offsets[0] = 0;
}

// fill packed (src, weight) pairs: weight = dis[src]
__global__ void fill_kernel(const int* __restrict__ row, const int* __restrict__ col,
                            const int* __restrict__ offsets, int* __restrict__ cursor,
                            int2* __restrict__ csr_sw, const float* __restrict__ dis, int E) {
    int e = blockIdx.x * blockDim.x + threadIdx.x;
    if (e < E) {
        int d = col[e];
        int s = row[e];
        int pos = offsets[d] + atomicAdd(&cursor[d], 1);
        csr_sw[pos] = make_int2(s, __float_as_int(dis[s]));
    }
}

// ---------------------------------------------------------------- aggregation
// scalar version (tiny F only), 2x-unrolled edge loop
template <typename TIn, typename TOut>
__global__ void agg_kernel(const TIn* __restrict__ h, const int* __restrict__ offsets,
                           const int2* __restrict__ csr_sw, const float* __restrict__ dis,
                           const float* __restrict__ bias, TOut* __restrict__ out,
                           int n, int F, int add_bias, int relu) {
    long long idx = (long long)blockIdx.x * blockDim.x + threadIdx.x;
    long long total = (long long)n * F;
    if (idx >= total) return;
    int i = (int)(idx / F);
    int f = (int)(idx % F);
    float di = dis[i];
    float acc = di * ldf(h, (size_t)i * F + f);
    float acc2 = 0.0f;
    int e0 = offsets[i], e1 = offsets[i + 1];
    int e = e0;
    for (; e + 1 < e1; e += 2) {
        int2 sw0 = csr_sw[e];
        int2 sw1 = csr_sw[e + 1];
        float v0 = ldf(h, (size_t)sw0.x * F + f);
        float v1 = ldf(h, (size_t)sw1.x * F + f);
        acc  += __int_as_float(sw0.y) * v0;
        acc2 += __int_as_float(sw1.y) * v1;
    }
    if (e < e1) {
        int2 sw = csr_sw[e];
        acc += __int_as_float(sw.y) * ldf(h, (size_t)sw.x * F + f);
    }
    acc = (acc + acc2) * di;
    if (add_bias) acc += bias[f];
    if (relu) acc = fmaxf(acc, 0.0f);
    stf(out, (size_t)idx, acc);
}

// L7 agg (F=2) fused with output dtype conversion
__global__ void agg2_out_kernel(const float* __restrict__ in, const int* __restrict__ offsets,
                                const int2* __restrict__ csr_sw, const float* __restrict__ dis,
                                const float* __restrict__ bias, void* __restrict__ out,
                                int n, const int* __restrict__ flag) {
    int idx = blockIdx.x * 256 + threadIdx.x;
    if (idx >= n * 2) return;
    int i = idx >> 1;
    int f = idx & 1;
    float di = dis[i];
    float acc = di * in[idx];
    float acc2 = 0.0f;
    int e0 = offsets[i], e1 = offsets[i + 1];
    int e = e0;
    for (; e + 1 < e1; e += 2) {
        int2 sw0 = csr_sw[e];
        int2 sw1 = csr_sw[e + 1];
        float v0 = in[(size_t)sw0.x * 2 + f];
        float v1 = in[(size_t)sw1.x * 2 + f];
        acc  += __int_as_float(sw0.y) * v0;
        acc2 += __int_as_float(sw1.y) * v1;
    }
    if (e < e1) {
        int2 sw = csr_sw[e];
        acc += __int_as_float(sw.y) * in[(size_t)sw.x * 2 + f];
    }
    acc = (acc + acc2) * di + bias[f];
    if (*flag) ((bf16*)out)[idx] = (bf16)acc;
    else       ((float*)out)[idx] = acc;
}

// vectorized: thread owns VEC consecutive features (16B loads).
// 4-deep gather pipeline.
template <int F, int DO_BIAS, int DO_RELU, typename TIn, typename TOut>
__global__ __launch_bounds__(256) void agg_vec_kernel(
        const TIn* __restrict__ h, const int* __restrict__ offsets,
        const int2* __restrict__ csr_sw, const float* __restrict__ dis,
        const float* __restrict__ bias, TOut* __restrict__ out, int n) {
    constexpr int VEC = 16 / sizeof(TIn);
    constexpr int CPL = F / VEC;
    int t = blockIdx.x * 256 + threadIdx.x;
    if (t >= n * CPL) return;
    int i = t / CPL;
    int c = t % CPL;
    int fbase = c * VEC;
    float di = dis[i];
    float acc[VEC], acc2[VEC];
    loadvec(h + (size_t)i * F + fbase, acc);
    #pragma unroll
    for (int v = 0; v < VEC; ++v) { acc[v] *= di; acc2[v] = 0.0f; }
    int e0 = offsets[i], e1 = offsets[i + 1];
    int e = e0;
    for (; e + 3 < e1; e += 4) {
        int2 sw0 = csr_sw[e];
        int2 sw1 = csr_sw[e + 1];
        int2 sw2 = csr_sw[e + 2];
        int2 sw3 = csr_sw[e + 3];
        float t0[VEC], t1[VEC], t2[VEC], t3[VEC];
        loadvec(h + (size_t)sw0.x * F + fbase, t0);
        loadvec(h + (size_t)sw1.x * F + fbase, t1);
        loadvec(h + (size_t)sw2.x * F + fbase, t2);
        loadvec(h + (size_t)sw3.x * F + fbase, t3);
        float d0 = __int_as_float(sw0.y);
        float d1 = __int_as_float(sw1.y);
        float d2 = __int_as_float(sw2.y);
        float d3 = __int_as_float(sw3.y);
        #pragma unroll
        for (int v = 0; v < VEC; ++v) {
            acc[v]  += d0 * t0[v];
            acc2[v] += d1 * t1[v];
            acc[v]  += d2 * t2[v];
            acc2[v] += d3 * t3[v];
        }
    }
    for (; e + 1 < e1; e += 2) {
        int2 sw0 = csr_sw[e];
        int2 sw1 = csr_sw[e + 1];
        float t0[VEC], t1[VEC];
        loadvec(h + (size_t)sw0.x * F + fbase, t0);
        loadvec(h + (size_t)sw1.x * F + fbase, t1);
        float d0 = __int_as_float(sw0.y);
        float d1 = __int_as_float(sw1.y);
        #pragma unroll
        for (int v = 0; v < VEC; ++v) {
            acc[v]  += d0 * t0[v];
            acc2[v] += d1 * t1[v];
        }
    }
    if (e < e1) {
        int2 sw = csr_sw[e];
        float dsv = __int_as_float(sw.y);
        float tmp[VEC];
        loadvec(h + (size_t)sw.x * F + fbase, tmp);
        #pragma unroll
        for (int v = 0; v < VEC; ++v) acc[v] += dsv * tmp[v];
    }
    #pragma unroll
    for (int v = 0; v < VEC; ++v) {
        acc[v] = (acc[v] + acc2[v]) * di;
        if (DO_BIAS) acc[v] += bias[fbase + v];
        if (DO_RELU) acc[v] = fmaxf(acc[v], 0.0f);
    }
    storevec<VEC>(out + (size_t)i * F + fbase, acc);
}

// ---------------------------------------------------------------- GEMMs
// L0 specialized: [M,3] @ [3,64] + b, relu.
__global__ __launch_bounds__(256) void gemm_k3_kernel(
        const float* __restrict__ A, const float* __restrict__ W,
        const float* __restrict__ bias, float* __restrict__ C, int M) {
    __shared__ float Ws[3][64];
    __shared__ float bs[64];
    if (threadIdx.x < 192) Ws[threadIdx.x >> 6][threadIdx.x & 63] = W[threadIdx.x];
    if (threadIdx.x < 64)  bs[threadIdx.x] = bias[threadIdx.x];
    __syncthreads();
    int t = blockIdx.x * 256 + threadIdx.x;
    if (t >= M * 16) return;
    int m = t >> 4;
    int c = (t & 15) << 2;
    float a0 = A[(size_t)m * 3], a1 = A[(size_t)m * 3 + 1], a2 = A[(size_t)m * 3 + 2];
    float4 o;
    o.x = fmaxf(a0 * Ws[0][c]     + a1 * Ws[1][c]     + a2 * Ws[2][c]     + bs[c],     0.f);
    o.y = fmaxf(a0 * Ws[0][c + 1] + a1 * Ws[1][c + 1] + a2 * Ws[2][c + 1] + bs[c + 1], 0.f);
    o.z = fmaxf(a0 * Ws[0][c + 2] + a1 * Ws[1][c + 2] + a2 * Ws[2][c + 2] + bs[c + 2], 0.f);
    o.w = fmaxf(a0 * Ws[0][c + 3] + a1 * Ws[1][c + 3] + a2 * Ws[2][c + 3] + bs[c + 3], 0.f);
    *(float4*)(C + (size_t)m * 64 + c) = o;
}

// L7 specialized: [M,256]bf16 @ [256,2]f32 -> [M,2]f32.
__global__ __launch_bounds__(256) void gemm_f2_kernel(
        const bf16* __restrict__ A, const float* __restrict__ W,
        float* __restrict__ C, int M) {
    __shared__ float Ws[256][2];
    for (int i = threadIdx.x; i < 512; i += 256) Ws[i >> 1][i & 1] = W[i];
    __syncthreads();
    int m = blockIdx.x * 256 + threadIdx.x;
    if (m >= M) return;
    const bf16* a = A + (size_t)m * 256;
    float acc0 = 0.f, acc1 = 0.f;
    #pragma unroll 4
    for (int k0 = 0; k0 < 256; k0 += 8) {
        float d[8];
        loadvec(a + k0, d);
        #pragma unroll
        for (int j = 0; j < 8; ++j) {
            acc0 += d[j] * Ws[k0 + j][0];
            acc1 += d[j] * Ws[k0 + j][1];
        }
    }
    C[(size_t)m * 2]     = acc0;
    C[(size_t)m * 2 + 1] = acc1;
}

// fp32 single-shot GEMM for K=64 (L1-L3)
template <typename TOut>
__global__ __launch_bounds__(256) void gemm_k64_kernel(
        const float* __restrict__ A, const float* __restrict__ W,
        const float* __restrict__ bias, TOut* __restrict__ C,
        int M, int Nc, int add_bias, int relu) {
    __shared__ float As[64][68];
    __shared__ float Bs[64][68];
    const int bm = blockIdx.x * 64;
    const int bn = blockIdx.y * 64;
    const int tid = threadIdx.x;
    #pragma unroll
    for (int l = 0; l < 4; ++l) {
        int lin = l * 256 + tid;
        int m = lin >> 4;
        int k = (lin & 15) << 2;
        int gm = bm + m; if (gm > M - 1) gm = M - 1;
        float4 v = *(const float4*)(A + (size_t)gm * 64 + k);
        As[k][m] = v.x; As[k + 1][m] = v.y; As[k + 2][m] = v.z; As[k + 3][m] = v.w;
    }
    #pragma unroll
    for (int l = 0; l < 4; ++l) {
        int lin = l * 256 + tid;
        int k = lin >> 4;
        int n = (lin & 15) << 2;
        *(float4*)(&Bs[k][n]) = *(const float4*)(W + (size_t)k * Nc + bn + n);
    }
    __syncthreads();
    const int tm = (tid >> 4) << 2;
    const int tn = (tid & 15) << 2;
    float acc[4][4] = {};
    #pragma unroll 8
    for (int k = 0; k < 64; ++k) {
        float a[4], b[4];
        #pragma unroll
        for (int i = 0; i < 4; ++i) a[i] = As[k][tm + i];
        #pragma unroll
        for (int j = 0; j < 4; ++j) b[j] = Bs[k][tn + j];
        #pragma unroll
        for (int i = 0; i < 4; ++i)
            #pragma unroll
            for (int j = 0; j < 4; ++j) acc[i][j] += a[i] * b[j];
    }
    #pragma unroll
    for (int i = 0; i < 4; ++i) {
        int gm = bm + tm + i;
        if (gm >= M) continue;
        #pragma unroll
        for (int j = 0; j < 4; ++j) {
            int gn = bn + tn + j;
            float v = acc[i][j];
            if (add_bias) v += bias[gn];
            if (relu) v = fmaxf(v, 0.0f);
            stf(C, (size_t)gm * Nc + gn, v);
        }
    }
}

// ---------------------------------------------------------------- MFMA GEMMs
// K=128 single-shot (L4): proven round-7 kernel.
template <int DO_BIAS, int DO_RELU>
__global__ __launch_bounds__(256) void gemm_mfma_k128_kernel(
        const bf16* __restrict__ A, const bf16* __restrict__ Bt,
        const float* __restrict__ bias, bf16* __restrict__ C,
        int M, int Nc) {
    __shared__ bf16 As[128 * 128];
    __shared__ bf16 Bs[128 * 128];
    const int tid  = threadIdx.x;
    const int wave = tid >> 6;
    const int lane = tid & 63;

    const int nwg  = (int)gridDim.x;
    const int orig = (int)blockIdx.x;
    const int q = nwg >> 3, r = nwg & 7;
    const int xcd = orig & 7;
    const int lin = orig >> 3;
    const int swz = (xcd < r ? xcd * (q + 1) : r * (q + 1) + (xcd - r) * q) + lin;
    const int nbn = Nc >> 7;
    const int bm = (swz / nbn) * 128;
    const int bn = (swz % nbn) * 128;

    const int wr = (wave >> 1) * 64;
    const int wc = (wave & 1) * 64;
    const int fm = lane & 15;
    const int fq = lane >> 4;

    #pragma unroll
    for (int p = 0; p < 8; ++p) {
        int idx = p * 256 + tid;
        int row = idx >> 4;
        int c   = idx & 15;
        int scol = (c ^ (row & 15)) << 3;
        int gm = bm + row; if (gm > M - 1) gm = M - 1;
        async16(A  + (size_t)gm * 128 + scol,        &As[idx * 8]);
        async16(Bt + (size_t)(bn + row) * 128 + scol, &Bs[idx * 8]);
    }
    asm volatile("s_waitcnt vmcnt(0)" ::: "memory");
    __builtin_amdgcn_s_barrier();

    floatx4 acc[4][4] = {};
    #pragma unroll
    for (int t = 0; t < 4; ++t) {
        short8 af[4], bfv[4];
        #pragma unroll
        for (int mt = 0; mt < 4; ++mt) {
            int rowa = wr + mt * 16 + fm;
            int ch = (4 * t + fq) ^ (rowa & 15);
            af[mt] = *(const short8*)(&As[rowa * 128 + ch * 8]);
        }
        #pragma unroll
        for (int ntc = 0; ntc < 4; ++ntc) {
            int rowb = wc + ntc * 16 + fm;
            int ch = (4 * t + fq) ^ (rowb & 15);
            bfv[ntc] = *(const short8*)(&Bs[rowb * 128 + ch * 8]);
        }
        #pragma unroll
        for (int mt = 0; mt < 4; ++mt)
            #pragma unroll
            for (int ntc = 0; ntc < 4; ++ntc)
                acc[mt][ntc] = __builtin_amdgcn_mfma_f32_16x16x32_bf16(
                    af[mt], bfv[ntc], acc[mt][ntc], 0, 0, 0);
    }

    #pragma unroll
    for (int mt = 0; mt < 4; ++mt) {
        #pragma unroll
        for (int r2 = 0; r2 < 4; ++r2) {
            int gm = bm + wr + mt * 16 + fq * 4 + r2;
            if (gm >= M) continue;
            #pragma unroll
            for (int ntc = 0; ntc < 4; ++ntc) {
                int gn = bn + wc + ntc * 16 + fm;
                float v = acc[mt][ntc][r2];
                if (DO_BIAS) v += bias[gn];
                if (DO_RELU) v = fmaxf(v, 0.0f);
                C[(size_t)gm * Nc + gn] = (bf16)v;
            }
        }
    }
}

// 256x256 phased MFMA GEMM (L5/L6): 512 thr (8 waves, 2Mx4N, per-wave 128x64),
// BK=32, 3 LDS slots (96KB), depth-2 prefetch, steady vmcnt(4).
// Minimal-barrier schedule — 1 barrier + 1 vmcnt per K-tile.
// Correctness: the single barrier (after vmcnt guard of tile t) both
// publishes tile-t loads to all waves AND separates tile t-1's last reads of
// slot sp=(t+2)%3=(t-1)%3 from tile t's stage into sp. Stage target sp never
// equals the read slot cur=t%3. All 4 stage chunks issue at tile top.
template <int DO_BIAS, int DO_RELU>
__global__ __launch_bounds__(512, 2) void gemm_mfma_256_kernel(
        const bf16* __restrict__ A,   // [M,K]
        const bf16* __restrict__ Bt,  // [Nc,K]
        const float* __restrict__ bias,
        bf16* __restrict__ C,         // [M,Nc]
        int M, int Nc, int K) {
    __shared__ bf16 As[3][256 * 32];
    __shared__ bf16 Bs[3][256 * 32];
    const int tid  = threadIdx.x;
    const int wave = tid >> 6;
    const int lane = tid & 63;
    const int wm = wave >> 2;        // 0..1: output rows [wm*128, +128)
    const int wn = wave & 3;         // 0..3: output cols [wn*64, +64)
    const int fm = lane & 15;
    const int fq = lane >> 4;

    // bijective XCD swizzle + column-fast decomposition
    const int nwg  = (int)gridDim.x;
    const int orig = (int)blockIdx.x;
    const int q = nwg >> 3, r = nwg & 7;
    const int xcd = orig & 7;
    const int lin = orig >> 3;
    const int swz = (xcd < r ? xcd * (q + 1) : r * (q + 1) + (xcd - r) * q) + lin;
    const int nbn = Nc >> 8;                 // 256-wide col blocks
    const int bm = (swz / nbn) * 256;
    const int bn = (swz % nbn) * 256;

    // staging: 1 chunk/thread per 128x32 half-tile (512 chunks)
    const int srl = tid >> 2;                 // 0..127 (row within half)
    const int sc  = tid & 3;                  // 16B chunk 0..3
    const int scol = (sc ^ ((srl >> 1) & 3)) << 3;   // swizzled source col (elems)
    int gmA0 = bm + srl;        if (gmA0 > M - 1) gmA0 = M - 1;
    int gmA1 = bm + 128 + srl;  if (gmA1 > M - 1) gmA1 = M - 1;
    const bf16* a0 = A  + (size_t)gmA0 * K + scol;
    const bf16* a1 = A  + (size_t)gmA1 * K + scol;
    const bf16* b0 = Bt + (size_t)(bn + srl) * K + scol;
    const bf16* b1 = Bt + (size_t)(bn + 128 + srl) * K + scol;
    const int ld0 = srl * 32 + sc * 8;          // LDS dest (elems), half0
    const int ld1 = (128 + srl) * 32 + sc * 8;  // half1

    const int nt = K >> 5;
    floatx4 acc[8][4] = {};

    auto stage = [&](int slot, int kt) {
        const int k0 = kt << 5;
        async16(a0 + k0, &As[slot][ld0]); async16(a1 + k0, &As[slot][ld1]);
        async16(b0 + k0, &Bs[slot][ld0]); async16(b1 + k0, &Bs[slot][ld1]);
    };

    // prologue: tiles 0,1 -> slots 0,1 (guard handled at loop top)
    stage(0, 0);
    if (nt > 1) stage(1, 1);

    int cur = 0;
    for (int t = 0; t < nt; ++t) {
        int sp = cur + 2; if (sp >= 3) sp -= 3;         // slot for tile t+2
        const bool pf = (t + 2) < nt;

        // guard tile t landed (tile t+1's 4 chunks may stay in flight),
        // publish to all waves, and fence t-1-reads vs stage-into-sp.
        if (t + 1 < nt) asm volatile("s_waitcnt vmcnt(4)" ::: "memory");
        else            asm volatile("s_waitcnt vmcnt(0)" ::: "memory");
        __builtin_amdgcn_s_barrier();
        if (pf) stage(sp, t + 2);

        short8 af[4], bfv[4];
        // ---- phase 0 (M-half 0) ----
        #pragma unroll
        for (int i = 0; i < 4; ++i) {
            int ra = wm * 128 + i * 16 + fm;
            af[i] = *(const short8*)(&As[cur][ra * 32 + ((fq ^ ((ra >> 1) & 3)) << 3)]);
        }
        #pragma unroll
        for (int j = 0; j < 4; ++j) {
            int rb = wn * 64 + j * 16 + fm;
            bfv[j] = *(const short8*)(&Bs[cur][rb * 32 + ((fq ^ ((rb >> 1) & 3)) << 3)]);
        }
        __builtin_amdgcn_s_setprio(1);
        #pragma unroll
        for (int i = 0; i < 4; ++i)
            #pragma unroll
            for (int j = 0; j < 4; ++j)
                acc[i][j] = __builtin_amdgcn_mfma_f32_16x16x32_bf16(
                    af[i], bfv[j], acc[i][j], 0, 0, 0);
        __builtin_amdgcn_s_setprio(0);

        // ---- phase 1 (M-half 1): reuse bfv ----
        #pragma unroll
        for (int i = 0; i < 4; ++i) {
            int ra = wm * 128 + 64 + i * 16 + fm;
            af[i] = *(const short8*)(&As[cur][ra * 32 + ((fq ^ ((ra >> 1) & 3)) << 3)]);
        }
        __builtin_amdgcn_s_setprio(1);
        #pragma unroll
        for (int i = 0; i < 4; ++i)
            #pragma unroll
            for (int j = 0; j < 4; ++j)
                acc[4 + i][j] = __builtin_amdgcn_mfma_f32_16x16x32_bf16(
                    af[i], bfv[j], acc[4 + i][j], 0, 0, 0);
        __builtin_amdgcn_s_setprio(0);

        ++cur; if (cur >= 3) cur = 0;
    }

    // epilogue: per-wave 128x64 block
    #pragma unroll
    for (int ig = 0; ig < 8; ++ig) {
        #pragma unroll
        for (int rr = 0; rr < 4; ++rr) {
            int gm = bm + wm * 128 + ig * 16 + fq * 4 + rr;
            if (gm >= M) continue;
            #pragma unroll
            for (int j = 0; j < 4; ++j) {
                int gn = bn + wn * 64 + j * 16 + fm;
                float v = acc[ig][j][rr];
                if (DO_BIAS) v += bias[gn];
                if (DO_RELU) v = fmaxf(v, 0.0f);
                C[(size_t)gm * Nc + gn] = (bf16)v;
            }
        }
    }
}

// ---------------------------------------------------------------- driver

static inline int cdiv(long long a, int b) { return (int)((a + b - 1) / b); }

extern "C" void kernel_launch(void* const* d_in, const int* in_sizes, int n_in,
                              void* d_out, int out_size, void* d_ws, size_t ws_size,
                              hipStream_t stream) {
    const int N = in_sizes[0] / 3;
    const int E = in_sizes[1] / 2;

    const int* edge_index = (const int*)d_in[1];
    const int* row = edge_index;       // sources
    const int* col = edge_index + E;   // destinations

    char* p = (char*)d_ws;
    auto alloc = [&](size_t bytes) {
        void* r = (void*)p;
        p += (bytes + 255) & ~(size_t)255;
        return r;
    };
    void* bufA    = alloc((size_t)N * 2048);
    void* bufB    = alloc((size_t)N * 1024);
    float* dis    = (float*)alloc((size_t)N * sizeof(float));
    int* offsets  = (int*)alloc((size_t)(N + 1) * sizeof(int));
    int* cursor   = (int*)alloc((size_t)N * sizeof(int));
    int2* csr_sw  = (int2*)alloc((size_t)E * sizeof(int2));
    int* flag     = (int*)alloc(256);
    int* blocksums = (int*)alloc((size_t)cdiv(N, 1024) * sizeof(int));
    const int WfL[5] = {0, 1, 2, 3, 7};
    float* Wf[8] = {};
    float* bf_[8];
    for (int t = 0; t < 5; ++t) {
        int L = WfL[t];
        Wf[L] = (float*)alloc((size_t)in_sizes[2 + 2 * L] * sizeof(float));
    }
    for (int L = 0; L < 8; ++L)
        bf_[L] = (float*)alloc((size_t)in_sizes[3 + 2 * L] * sizeof(float));
    bf16* Wt4 = (bf16*)alloc((size_t)128 * 1024 * sizeof(bf16));
    bf16* Wt5 = (bf16*)alloc((size_t)1024 * 512 * sizeof(bf16));
    bf16* Wt6 = (bf16*)alloc((size_t)512 * 256 * sizeof(bf16));
    size_t needed = (size_t)(p - (char*)d_ws);
    if (ws_size < needed) return;

    float* fA = (float*)bufA;  bf16* hA = (bf16*)bufA;
    float* fB = (float*)bufB;  bf16* hB = (bf16*)bufB;

    const int T = 256;

    // ---- dtype detect ----
    detect_dtype_kernel<<<1, 256, 0, stream>>>((const unsigned short*)d_in[0], flag);

    // ---- fused fp32 converts ----
    {
        CvtJobs cj{};
        int idx = 0, cum = 0;
        auto add = [&](const void* s, float* d, int n) {
            cj.src[idx] = s; cj.dst[idx] = d; cj.off[idx] = cum; cum += n; ++idx;
        };
        add(d_in[0], fA, N * 3);
        for (int t = 0; t < 5; ++t) {
            int L = WfL[t];
            add(d_in[2 + 2 * L], Wf[L], in_sizes[2 + 2 * L]);
        }
        for (int L = 0; L < 8; ++L)
            add(d_in[3 + 2 * L], bf_[L], in_sizes[3 + 2 * L]);
        cj.off[idx] = cum; cj.cnt = idx;
        cvt_fused_kernel<<<cdiv(cum, T), T, 0, stream>>>(cj, flag);
    }

    // ---- fused bf16 weight transposes ----
    {
        WtJobs wj{};
        wj.src[0] = d_in[2 + 2 * 4]; wj.dst[0] = Wt4; wj.K[0] = 128;  wj.N[0] = 1024;
        wj.src[1] = d_in[2 + 2 * 5]; wj.dst[1] = Wt5; wj.K[1] = 1024; wj.N[1] = 512;
        wj.src[2] = d_in[2 + 2 * 6]; wj.dst[2] = Wt6; wj.K[2] = 512;  wj.N[2] = 256;
        wj.off[0] = 0;
        wj.off[1] = 128 * 1024;
        wj.off[2] = 128 * 1024 + 1024 * 512;
        wj.off[3] = 128 * 1024 + 1024 * 512 + 512 * 256;
        wt_fused_kernel<<<cdiv(wj.off[3], T), T, 0, stream>>>(wj, flag);
    }

    // ---- CSR build ----
    {
        zero_int_kernel<<<cdiv(N, T), T, 0, stream>>>(cursor, N);
        hist_kernel<<<cdiv(E, T), T, 0, stream>>>(col, cursor, E);
        int nb = cdiv(N, 1024);
        scan_reduce_kernel<<<nb, 1024, 0, stream>>>(cursor, blocksums, N);
        scan_blocksums_kernel<<<1, 1024, 0, stream>>>(blocksums, nb);
        scan_final_kernel<<<nb, 1024, 0, stream>>>(cursor, blocksums, offsets, dis, N);
        fill_kernel<<<cdiv(E, T), T, 0, stream>>>(row, col, offsets, cursor, csr_sw, dis, E);
    }

    // L0: 3->64 aggFirst
    agg_kernel<float, float><<<cdiv((long long)N * 3, T), T, 0, stream>>>(
        fA, offsets, csr_sw, dis, nullptr, fB, N, 3, 0, 0);
    gemm_k3_kernel<<<cdiv((long long)N * 16, T), T, 0, stream>>>(fB, Wf[0], bf_[0], fA, N);

    // L1: 64->64 gemmFirst
    {
        dim3 g(cdiv(N, 64), 1);
        gemm_k64_kernel<float><<<g, 256, 0, stream>>>(fA, Wf[1], nullptr, fB, N, 64, 0, 0);
        agg_vec_kernel<64, 1, 1, float, float><<<cdiv((long long)N * 16, T), T, 0, stream>>>(
            fB, offsets, csr_sw, dis, bf_[1], fA, N);
    }

    // L2: 64->64 same
    {
        dim3 g(cdiv(N, 64), 1);
        gemm_k64_kernel<float><<<g, 256, 0, stream>>>(fA, Wf[2], nullptr, fB, N, 64, 0, 0);
        agg_vec_kernel<64, 1, 1, float, float><<<cdiv((long long)N * 16, T), T, 0, stream>>>(
            fB, offsets, csr_sw, dis, bf_[2], fA, N);
    }

    // L3: 64->128 aggFirst
    {
        agg_vec_kernel<64, 0, 0, float, float><<<cdiv((long long)N * 16, T), T, 0, stream>>>(
            fA, offsets, csr_sw, dis, nullptr, fB, N);
        dim3 g(cdiv(N, 64), 2);
        gemm_k64_kernel<bf16><<<g, 256, 0, stream>>>(fB, Wf[3], bf_[3], hA, N, 128, 1, 1);
    }

    // L4: 128->1024 aggFirst: agg_vec -> hB, single-shot MFMA -> hA
    {
        agg_vec_kernel<128, 0, 0, bf16, bf16><<<cdiv((long long)N * 16, T), T, 0, stream>>>(
            hA, offsets, csr_sw, dis, nullptr, hB, N);
        int nwg = cdiv(N, 128) * (1024 / 128);
        gemm_mfma_k128_kernel<1, 1><<<nwg, 256, 0, stream>>>(hB, Wt4, bf_[4], hA, N, 1024);
    }

    // L5: 1024->512 gemmFirst: 256x256 phased MFMA -> hB, agg_vec -> hA
    {
        int nwg = cdiv(N, 256) * (512 / 256);
        gemm_mfma_256_kernel<0, 0><<<nwg, 512, 0, stream>>>(hA, Wt5, nullptr, hB, N, 512, 1024);
        agg_vec_kernel<512, 1, 1, bf16, bf16><<<cdiv((long long)N * 64, T), T, 0, stream>>>(
            hB, offsets, csr_sw, dis, bf_[5], hA, N);
    }

    // L6: 512->256 gemmFirst: 256x256 phased MFMA -> hB, agg_vec -> hA
    {
        int nwg = cdiv(N, 256) * (256 / 256);
        gemm_mfma_256_kernel<0, 0><<<nwg, 512, 0, stream>>>(hA, Wt6, nullptr, hB, N, 256, 512);
        agg_vec_kernel<256, 1, 1, bf16, bf16><<<cdiv((long long)N * 32, T), T, 0, stream>>>(
            hB, offsets, csr_sw, dis, bf_[6], hA, N);
    }

    // L7: 256->2 gemmFirst: vectorized f2 GEMM -> fB, fused agg+out -> d_out
    {
        gemm_f2_kernel<<<cdiv(N, T), T, 0, stream>>>(hA, Wf[7], fB, N);
        agg2_out_kernel<<<cdiv((long long)N * 2, T), T, 0, stream>>>(
            fB, offsets, csr_sw, dis, bf_[7], d_out, N, flag);
    }
}

// Round 13
// 456.734 us; speedup vs baseline: 1.0358x; 1.0358x over previous
//
#include <hip/hip_runtime.h>
#include <hip/hip_bf16.h>

typedef __hip_bfloat16 bf16;
typedef __attribute__((ext_vector_type(8))) short short8;
typedef __attribute__((ext_vector_type(4))) float floatx4;

// ---- dtype helpers ----
__device__ inline float ldf(const float* p, size_t i) { return p[i]; }
__device__ inline float ldf(const bf16* p, size_t i) { return (float)p[i]; }
__device__ inline void stf(float* p, size_t i, float v) { p[i] = v; }
__device__ inline void stf(bf16* p, size_t i, float v) { p[i] = (bf16)v; }

// ---- async global->LDS 16B copy ----
__device__ inline void async16(const bf16* g, bf16* l) {
    __builtin_amdgcn_global_load_lds(
        (const __attribute__((address_space(1))) void*)g,
        (__attribute__((address_space(3))) void*)l, 16, 0, 0);
}

// ---- 16B vector load of VEC elements -> fp32 lanes ----
__device__ inline void loadvec(const float* __restrict__ p, float* d) {   // VEC=4
    float4 v = *(const float4*)p;
    d[0] = v.x; d[1] = v.y; d[2] = v.z; d[3] = v.w;
}
__device__ inline void loadvec(const bf16* __restrict__ p, float* d) {    // VEC=8
    uint4 u = *(const uint4*)p;
    const unsigned* w = (const unsigned*)&u;
    #pragma unroll
    for (int j = 0; j < 4; ++j) {
        d[2 * j]     = __uint_as_float(w[j] << 16);
        d[2 * j + 1] = __uint_as_float(w[j] & 0xffff0000u);
    }
}
template <int VEC, typename TOut>
__device__ inline void storevec(TOut* __restrict__ p, const float* d) {
    if constexpr (sizeof(TOut) == 4) {
        #pragma unroll
        for (int j = 0; j < VEC; j += 4) {
            float4 v = {d[j], d[j + 1], d[j + 2], d[j + 3]};
            *(float4*)(p + j) = v;
        }
    } else {
        unsigned w[VEC / 2];
        #pragma unroll
        for (int j = 0; j < VEC / 2; ++j) {
            bf16 lo = (bf16)d[2 * j], hi = (bf16)d[2 * j + 1];
            w[j] = ((unsigned)*(unsigned short*)&hi << 16) | (unsigned)*(unsigned short*)&lo;
        }
        if constexpr (VEC == 8) *(uint4*)p = *(uint4*)&w[0];
        else                    *(uint2*)p = *(uint2*)&w[0];
    }
}

// ---------------------------------------------------------------- dtype detect
__global__ void detect_dtype_kernel(const unsigned short* __restrict__ x, int* __restrict__ flag) {
    __shared__ float s[256];
    float m = 0.0f;
    for (int i = threadIdx.x; i < 512; i += 256) {
        unsigned int u = ((unsigned int)x[i]) << 16;
        float v = __uint_as_float(u);
        if (!isnan(v)) m = fmaxf(m, fabsf(v));
    }
    s[threadIdx.x] = m;
    __syncthreads();
    for (int o = 128; o > 0; o >>= 1) {
        if (threadIdx.x < (unsigned)o) s[threadIdx.x] = fmaxf(s[threadIdx.x], s[threadIdx.x + o]);
        __syncthreads();
    }
    if (threadIdx.x == 0) flag[0] = (s[0] > 1e3f) ? 0 : 1;
}

// ---------------------------------------------------------------- fused converts
struct CvtJobs {
    const void* src[14];
    float* dst[14];
    int off[15];
    int cnt;
};
__global__ void cvt_fused_kernel(CvtJobs j, const int* __restrict__ flag) {
    int t = blockIdx.x * 256 + threadIdx.x;
    if (t >= j.off[j.cnt]) return;
    int k = 0;
    while (t >= j.off[k + 1]) ++k;
    int e = t - j.off[k];
    float v = *flag ? (float)((const bf16*)j.src[k])[e] : ((const float*)j.src[k])[e];
    j.dst[k][e] = v;
}

// W[K][N] (raw dtype per flag) -> Wt[N][K] bf16, three jobs fused
struct WtJobs {
    const void* src[3];
    bf16* dst[3];
    int K[3], N[3];
    int off[4];
};
__global__ void wt_fused_kernel(WtJobs j, const int* __restrict__ flag) {
    int t = blockIdx.x * 256 + threadIdx.x;
    if (t >= j.off[3]) return;
    int k_ = 0;
    while (t >= j.off[k_ + 1]) ++k_;
    int e = t - j.off[k_];
    int K = j.K[k_], Nn = j.N[k_];
    int n = e / K, kk = e % K;
    size_t si = (size_t)kk * Nn + n;
    float v = *flag ? (float)((const bf16*)j.src[k_])[si] : ((const float*)j.src[k_])[si];
    j.dst[k_][e] = (bf16)v;
}

// ---------------------------------------------------------------- CSR build
__global__ void zero_int_kernel(int* a, int n) {
    int i = blockIdx.x * blockDim.x + threadIdx.x;
    if (i < n) a[i] = 0;
}

__global__ void hist_kernel(const int* __restrict__ col, int* __restrict__ counts, int E) {
    int e = blockIdx.x * blockDim.x + threadIdx.x;
    if (e < E) atomicAdd(&counts[col[e]], 1);
}

// ---- 3-pass device-wide exclusive scan ----
__global__ void scan_reduce_kernel(const int* __restrict__ counts, int* __restrict__ bs, int n) {
    __shared__ int s[1024];
    int i = blockIdx.x * 1024 + threadIdx.x;
    s[threadIdx.x] = (i < n) ? counts[i] : 0;
    __syncthreads();
    for (int o = 512; o > 0; o >>= 1) {
        if (threadIdx.x < (unsigned)o) s[threadIdx.x] += s[threadIdx.x + o];
        __syncthreads();
    }
    if (threadIdx.x == 0) bs[blockIdx.x] = s[0];
}

__global__ void scan_blocksums_kernel(int* __restrict__ bs, int nb) {
    __shared__ int s[1024];
    int v = (threadIdx.x < (unsigned)nb) ? bs[threadIdx.x] : 0;
    s[threadIdx.x] = v;
    __syncthreads();
    for (int off = 1; off < 1024; off <<= 1) {
        int t = (threadIdx.x >= (unsigned)off) ? s[threadIdx.x - off] : 0;
        __syncthreads();
        s[threadIdx.x] += t;
        __syncthreads();
    }
    if (threadIdx.x < (unsigned)nb) bs[threadIdx.x] = s[threadIdx.x] - v;  // exclusive
}

__global__ void scan_final_kernel(int* __restrict__ counts, const int* __restrict__ bs,
                                  int* __restrict__ offsets, float* __restrict__ dis, int n) {
    __shared__ int s[1024];
    int i = blockIdx.x * 1024 + threadIdx.x;
    int v = (i < n) ? counts[i] : 0;
    if (i < n) { dis[i] = rsqrtf((float)(v + 1)); counts[i] = 0; }
    s[threadIdx.x] = v;
    __syncthreads();
    for (int off = 1; off < 1024; off <<= 1) {
        int t = (threadIdx.x >= (unsigned)off) ? s[threadIdx.x - off] : 0;
        __syncthreads();
        s[threadIdx.x] += t;
        __syncthreads();
    }
    if (i < n) offsets[i + 1] = s[threadIdx.x] + bs[blockIdx.x];
    if (i == 0) offsets[0] = 0;
}

// fill packed (src, weight) pairs: weight = dis[src]
__global__ void fill_kernel(const int* __restrict__ row, const int* __restrict__ col,
                            const int* __restrict__ offsets, int* __restrict__ cursor,
                            int2* __restrict__ csr_sw, const float* __restrict__ dis, int E) {
    int e = blockIdx.x * blockDim.x + threadIdx.x;
    if (e < E) {
        int d = col[e];
        int s = row[e];
        int pos = offsets[d] + atomicAdd(&cursor[d], 1);
        csr_sw[pos] = make_int2(s, __float_as_int(dis[s]));
    }
}

// ---------------------------------------------------------------- aggregation
// scalar version (tiny F only), 2x-unrolled edge loop
template <typename TIn, typename TOut>
__global__ void agg_kernel(const TIn* __restrict__ h, const int* __restrict__ offsets,
                           const int2* __restrict__ csr_sw, const float* __restrict__ dis,
                           const float* __restrict__ bias, TOut* __restrict__ out,
                           int n, int F, int add_bias, int relu) {
    long long idx = (long long)blockIdx.x * blockDim.x + threadIdx.x;
    long long total = (long long)n * F;
    if (idx >= total) return;
    int i = (int)(idx / F);
    int f = (int)(idx % F);
    float di = dis[i];
    float acc = di * ldf(h, (size_t)i * F + f);
    float acc2 = 0.0f;
    int e0 = offsets[i], e1 = offsets[i + 1];
    int e = e0;
    for (; e + 1 < e1; e += 2) {
        int2 sw0 = csr_sw[e];
        int2 sw1 = csr_sw[e + 1];
        float v0 = ldf(h, (size_t)sw0.x * F + f);
        float v1 = ldf(h, (size_t)sw1.x * F + f);
        acc  += __int_as_float(sw0.y) * v0;
        acc2 += __int_as_float(sw1.y) * v1;
    }
    if (e < e1) {
        int2 sw = csr_sw[e];
        acc += __int_as_float(sw.y) * ldf(h, (size_t)sw.x * F + f);
    }
    acc = (acc + acc2) * di;
    if (add_bias) acc += bias[f];
    if (relu) acc = fmaxf(acc, 0.0f);
    stf(out, (size_t)idx, acc);
}

// L7 agg (F=2) fused with output dtype conversion
__global__ void agg2_out_kernel(const float* __restrict__ in, const int* __restrict__ offsets,
                                const int2* __restrict__ csr_sw, const float* __restrict__ dis,
                                const float* __restrict__ bias, void* __restrict__ out,
                                int n, const int* __restrict__ flag) {
    int idx = blockIdx.x * 256 + threadIdx.x;
    if (idx >= n * 2) return;
    int i = idx >> 1;
    int f = idx & 1;
    float di = dis[i];
    float acc = di * in[idx];
    float acc2 = 0.0f;
    int e0 = offsets[i], e1 = offsets[i + 1];
    int e = e0;
    for (; e + 1 < e1; e += 2) {
        int2 sw0 = csr_sw[e];
        int2 sw1 = csr_sw[e + 1];
        float v0 = in[(size_t)sw0.x * 2 + f];
        float v1 = in[(size_t)sw1.x * 2 + f];
        acc  += __int_as_float(sw0.y) * v0;
        acc2 += __int_as_float(sw1.y) * v1;
    }
    if (e < e1) {
        int2 sw = csr_sw[e];
        acc += __int_as_float(sw.y) * in[(size_t)sw.x * 2 + f];
    }
    acc = (acc + acc2) * di + bias[f];
    if (*flag) ((bf16*)out)[idx] = (bf16)acc;
    else       ((float*)out)[idx] = acc;
}

// vectorized: thread owns VEC consecutive features (16B loads).
// 4-deep gather pipeline.
template <int F, int DO_BIAS, int DO_RELU, typename TIn, typename TOut>
__global__ __launch_bounds__(256) void agg_vec_kernel(
        const TIn* __restrict__ h, const int* __restrict__ offsets,
        const int2* __restrict__ csr_sw, const float* __restrict__ dis,
        const float* __restrict__ bias, TOut* __restrict__ out, int n) {
    constexpr int VEC = 16 / sizeof(TIn);
    constexpr int CPL = F / VEC;
    int t = blockIdx.x * 256 + threadIdx.x;
    if (t >= n * CPL) return;
    int i = t / CPL;
    int c = t % CPL;
    int fbase = c * VEC;
    float di = dis[i];
    float acc[VEC], acc2[VEC];
    loadvec(h + (size_t)i * F + fbase, acc);
    #pragma unroll
    for (int v = 0; v < VEC; ++v) { acc[v] *= di; acc2[v] = 0.0f; }
    int e0 = offsets[i], e1 = offsets[i + 1];
    int e = e0;
    for (; e + 3 < e1; e += 4) {
        int2 sw0 = csr_sw[e];
        int2 sw1 = csr_sw[e + 1];
        int2 sw2 = csr_sw[e + 2];
        int2 sw3 = csr_sw[e + 3];
        float t0[VEC], t1[VEC], t2[VEC], t3[VEC];
        loadvec(h + (size_t)sw0.x * F + fbase, t0);
        loadvec(h + (size_t)sw1.x * F + fbase, t1);
        loadvec(h + (size_t)sw2.x * F + fbase, t2);
        loadvec(h + (size_t)sw3.x * F + fbase, t3);
        float d0 = __int_as_float(sw0.y);
        float d1 = __int_as_float(sw1.y);
        float d2 = __int_as_float(sw2.y);
        float d3 = __int_as_float(sw3.y);
        #pragma unroll
        for (int v = 0; v < VEC; ++v) {
            acc[v]  += d0 * t0[v];
            acc2[v] += d1 * t1[v];
            acc[v]  += d2 * t2[v];
            acc2[v] += d3 * t3[v];
        }
    }
    for (; e + 1 < e1; e += 2) {
        int2 sw0 = csr_sw[e];
        int2 sw1 = csr_sw[e + 1];
        float t0[VEC], t1[VEC];
        loadvec(h + (size_t)sw0.x * F + fbase, t0);
        loadvec(h + (size_t)sw1.x * F + fbase, t1);
        float d0 = __int_as_float(sw0.y);
        float d1 = __int_as_float(sw1.y);
        #pragma unroll
        for (int v = 0; v < VEC; ++v) {
            acc[v]  += d0 * t0[v];
            acc2[v] += d1 * t1[v];
        }
    }
    if (e < e1) {
        int2 sw = csr_sw[e];
        float dsv = __int_as_float(sw.y);
        float tmp[VEC];
        loadvec(h + (size_t)sw.x * F + fbase, tmp);
        #pragma unroll
        for (int v = 0; v < VEC; ++v) acc[v] += dsv * tmp[v];
    }
    #pragma unroll
    for (int v = 0; v < VEC; ++v) {
        acc[v] = (acc[v] + acc2[v]) * di;
        if (DO_BIAS) acc[v] += bias[fbase + v];
        if (DO_RELU) acc[v] = fmaxf(acc[v], 0.0f);
    }
    storevec<VEC>(out + (size_t)i * F + fbase, acc);
}

// ---------------------------------------------------------------- GEMMs
// L0 specialized: [M,3] @ [3,64] + b, relu.
__global__ __launch_bounds__(256) void gemm_k3_kernel(
        const float* __restrict__ A, const float* __restrict__ W,
        const float* __restrict__ bias, float* __restrict__ C, int M) {
    __shared__ float Ws[3][64];
    __shared__ float bs[64];
    if (threadIdx.x < 192) Ws[threadIdx.x >> 6][threadIdx.x & 63] = W[threadIdx.x];
    if (threadIdx.x < 64)  bs[threadIdx.x] = bias[threadIdx.x];
    __syncthreads();
    int t = blockIdx.x * 256 + threadIdx.x;
    if (t >= M * 16) return;
    int m = t >> 4;
    int c = (t & 15) << 2;
    float a0 = A[(size_t)m * 3], a1 = A[(size_t)m * 3 + 1], a2 = A[(size_t)m * 3 + 2];
    float4 o;
    o.x = fmaxf(a0 * Ws[0][c]     + a1 * Ws[1][c]     + a2 * Ws[2][c]     + bs[c],     0.f);
    o.y = fmaxf(a0 * Ws[0][c + 1] + a1 * Ws[1][c + 1] + a2 * Ws[2][c + 1] + bs[c + 1], 0.f);
    o.z = fmaxf(a0 * Ws[0][c + 2] + a1 * Ws[1][c + 2] + a2 * Ws[2][c + 2] + bs[c + 2], 0.f);
    o.w = fmaxf(a0 * Ws[0][c + 3] + a1 * Ws[1][c + 3] + a2 * Ws[2][c + 3] + bs[c + 3], 0.f);
    *(float4*)(C + (size_t)m * 64 + c) = o;
}

// L7 specialized: [M,256]bf16 @ [256,2]f32 -> [M,2]f32.
__global__ __launch_bounds__(256) void gemm_f2_kernel(
        const bf16* __restrict__ A, const float* __restrict__ W,
        float* __restrict__ C, int M) {
    __shared__ float Ws[256][2];
    for (int i = threadIdx.x; i < 512; i += 256) Ws[i >> 1][i & 1] = W[i];
    __syncthreads();
    int m = blockIdx.x * 256 + threadIdx.x;
    if (m >= M) return;
    const bf16* a = A + (size_t)m * 256;
    float acc0 = 0.f, acc1 = 0.f;
    #pragma unroll 4
    for (int k0 = 0; k0 < 256; k0 += 8) {
        float d[8];
        loadvec(a + k0, d);
        #pragma unroll
        for (int j = 0; j < 8; ++j) {
            acc0 += d[j] * Ws[k0 + j][0];
            acc1 += d[j] * Ws[k0 + j][1];
        }
    }
    C[(size_t)m * 2]     = acc0;
    C[(size_t)m * 2 + 1] = acc1;
}

// fp32 single-shot GEMM for K=64 (L1-L3)
template <typename TOut>
__global__ __launch_bounds__(256) void gemm_k64_kernel(
        const float* __restrict__ A, const float* __restrict__ W,
        const float* __restrict__ bias, TOut* __restrict__ C,
        int M, int Nc, int add_bias, int relu) {
    __shared__ float As[64][68];
    __shared__ float Bs[64][68];
    const int bm = blockIdx.x * 64;
    const int bn = blockIdx.y * 64;
    const int tid = threadIdx.x;
    #pragma unroll
    for (int l = 0; l < 4; ++l) {
        int lin = l * 256 + tid;
        int m = lin >> 4;
        int k = (lin & 15) << 2;
        int gm = bm + m; if (gm > M - 1) gm = M - 1;
        float4 v = *(const float4*)(A + (size_t)gm * 64 + k);
        As[k][m] = v.x; As[k + 1][m] = v.y; As[k + 2][m] = v.z; As[k + 3][m] = v.w;
    }
    #pragma unroll
    for (int l = 0; l < 4; ++l) {
        int lin = l * 256 + tid;
        int k = lin >> 4;
        int n = (lin & 15) << 2;
        *(float4*)(&Bs[k][n]) = *(const float4*)(W + (size_t)k * Nc + bn + n);
    }
    __syncthreads();
    const int tm = (tid >> 4) << 2;
    const int tn = (tid & 15) << 2;
    float acc[4][4] = {};
    #pragma unroll 8
    for (int k = 0; k < 64; ++k) {
        float a[4], b[4];
        #pragma unroll
        for (int i = 0; i < 4; ++i) a[i] = As[k][tm + i];
        #pragma unroll
        for (int j = 0; j < 4; ++j) b[j] = Bs[k][tn + j];
        #pragma unroll
        for (int i = 0; i < 4; ++i)
            #pragma unroll
            for (int j = 0; j < 4; ++j) acc[i][j] += a[i] * b[j];
    }
    #pragma unroll
    for (int i = 0; i < 4; ++i) {
        int gm = bm + tm + i;
        if (gm >= M) continue;
        #pragma unroll
        for (int j = 0; j < 4; ++j) {
            int gn = bn + tn + j;
            float v = acc[i][j];
            if (add_bias) v += bias[gn];
            if (relu) v = fmaxf(v, 0.0f);
            stf(C, (size_t)gm * Nc + gn, v);
        }
    }
}

// ---------------------------------------------------------------- MFMA GEMMs
// K=128 single-shot (L4): proven round-7 kernel.
template <int DO_BIAS, int DO_RELU>
__global__ __launch_bounds__(256) void gemm_mfma_k128_kernel(
        const bf16* __restrict__ A, const bf16* __restrict__ Bt,
        const float* __restrict__ bias, bf16* __restrict__ C,
        int M, int Nc) {
    __shared__ bf16 As[128 * 128];
    __shared__ bf16 Bs[128 * 128];
    const int tid  = threadIdx.x;
    const int wave = tid >> 6;
    const int lane = tid & 63;

    const int nwg  = (int)gridDim.x;
    const int orig = (int)blockIdx.x;
    const int q = nwg >> 3, r = nwg & 7;
    const int xcd = orig & 7;
    const int lin = orig >> 3;
    const int swz = (xcd < r ? xcd * (q + 1) : r * (q + 1) + (xcd - r) * q) + lin;
    const int nbn = Nc >> 7;
    const int bm = (swz / nbn) * 128;
    const int bn = (swz % nbn) * 128;

    const int wr = (wave >> 1) * 64;
    const int wc = (wave & 1) * 64;
    const int fm = lane & 15;
    const int fq = lane >> 4;

    #pragma unroll
    for (int p = 0; p < 8; ++p) {
        int idx = p * 256 + tid;
        int row = idx >> 4;
        int c   = idx & 15;
        int scol = (c ^ (row & 15)) << 3;
        int gm = bm + row; if (gm > M - 1) gm = M - 1;
        async16(A  + (size_t)gm * 128 + scol,        &As[idx * 8]);
        async16(Bt + (size_t)(bn + row) * 128 + scol, &Bs[idx * 8]);
    }
    asm volatile("s_waitcnt vmcnt(0)" ::: "memory");
    __builtin_amdgcn_s_barrier();

    floatx4 acc[4][4] = {};
    #pragma unroll
    for (int t = 0; t < 4; ++t) {
        short8 af[4], bfv[4];
        #pragma unroll
        for (int mt = 0; mt < 4; ++mt) {
            int rowa = wr + mt * 16 + fm;
            int ch = (4 * t + fq) ^ (rowa & 15);
            af[mt] = *(const short8*)(&As[rowa * 128 + ch * 8]);
        }
        #pragma unroll
        for (int ntc = 0; ntc < 4; ++ntc) {
            int rowb = wc + ntc * 16 + fm;
            int ch = (4 * t + fq) ^ (rowb & 15);
            bfv[ntc] = *(const short8*)(&Bs[rowb * 128 + ch * 8]);
        }
        #pragma unroll
        for (int mt = 0; mt < 4; ++mt)
            #pragma unroll
            for (int ntc = 0; ntc < 4; ++ntc)
                acc[mt][ntc] = __builtin_amdgcn_mfma_f32_16x16x32_bf16(
                    af[mt], bfv[ntc], acc[mt][ntc], 0, 0, 0);
    }

    #pragma unroll
    for (int mt = 0; mt < 4; ++mt) {
        #pragma unroll
        for (int r2 = 0; r2 < 4; ++r2) {
            int gm = bm + wr + mt * 16 + fq * 4 + r2;
            if (gm >= M) continue;
            #pragma unroll
            for (int ntc = 0; ntc < 4; ++ntc) {
                int gn = bn + wc + ntc * 16 + fm;
                float v = acc[mt][ntc][r2];
                if (DO_BIAS) v += bias[gn];
                if (DO_RELU) v = fmaxf(v, 0.0f);
                C[(size_t)gm * Nc + gn] = (bf16)v;
            }
        }
    }
}

// 256x256 phased MFMA GEMM (L5/L6) — ROUND-9 PROVEN SCHEDULE (76.7us on L5):
// 512 thr (8 waves, 2Mx4N, per-wave 128x64), BK=32, 3 LDS slots (96KB),
// depth-2 prefetch, steady vmcnt(4), K-tile split into two 16-MFMA phases
// with barrier pacing + setprio; B-fragments held across the phase pair;
// stage A-halves in ph0, B-halves in ph1. Round-12 A/B showed removing the
// pacing barriers REGRESSES (87.6us) — they create the wave-interleave.
template <int DO_BIAS, int DO_RELU>
__global__ __launch_bounds__(512, 2) void gemm_mfma_256_kernel(
        const bf16* __restrict__ A,   // [M,K]
        const bf16* __restrict__ Bt,  // [Nc,K]
        const float* __restrict__ bias,
        bf16* __restrict__ C,         // [M,Nc]
        int M, int Nc, int K) {
    __shared__ bf16 As[3][256 * 32];
    __shared__ bf16 Bs[3][256 * 32];
    const int tid  = threadIdx.x;
    const int wave = tid >> 6;
    const int lane = tid & 63;
    const int wm = wave >> 2;        // 0..1: output rows [wm*128, +128)
    const int wn = wave & 3;         // 0..3: output cols [wn*64, +64)
    const int fm = lane & 15;
    const int fq = lane >> 4;

    // bijective XCD swizzle + column-fast decomposition
    const int nwg  = (int)gridDim.x;
    const int orig = (int)blockIdx.x;
    const int q = nwg >> 3, r = nwg & 7;
    const int xcd = orig & 7;
    const int lin = orig >> 3;
    const int swz = (xcd < r ? xcd * (q + 1) : r * (q + 1) + (xcd - r) * q) + lin;
    const int nbn = Nc >> 8;                 // 256-wide col blocks
    const int bm = (swz / nbn) * 256;
    const int bn = (swz % nbn) * 256;

    // staging: 1 chunk/thread per 128x32 half-tile (512 chunks)
    const int srl = tid >> 2;                 // 0..127 (row within half)
    const int sc  = tid & 3;                  // 16B chunk 0..3
    const int scol = (sc ^ ((srl >> 1) & 3)) << 3;   // swizzled source col (elems)
    int gmA0 = bm + srl;        if (gmA0 > M - 1) gmA0 = M - 1;
    int gmA1 = bm + 128 + srl;  if (gmA1 > M - 1) gmA1 = M - 1;
    const bf16* a0 = A  + (size_t)gmA0 * K + scol;
    const bf16* a1 = A  + (size_t)gmA1 * K + scol;
    const bf16* b0 = Bt + (size_t)(bn + srl) * K + scol;
    const bf16* b1 = Bt + (size_t)(bn + 128 + srl) * K + scol;
    const int ld0 = srl * 32 + sc * 8;          // LDS dest (elems), half0
    const int ld1 = (128 + srl) * 32 + sc * 8;  // half1

    const int nt = K >> 5;
    floatx4 acc[8][4] = {};

    // prologue: tiles 0,1 -> slots 0,1 (issue order matters for vmcnt ledger)
    async16(a0,      &As[0][ld0]); async16(a1,      &As[0][ld1]);
    async16(b0,      &Bs[0][ld0]); async16(b1,      &Bs[0][ld1]);
    async16(a0 + 32, &As[1][ld0]); async16(a1 + 32, &As[1][ld1]);
    async16(b0 + 32, &Bs[1][ld0]); async16(b1 + 32, &Bs[1][ld1]);
    asm volatile("s_waitcnt vmcnt(4)" ::: "memory");   // tile0's 4 landed
    __builtin_amdgcn_s_barrier();

    int cur = 0;
    for (int t = 0; t < nt; ++t) {
        int sp = cur + 2; if (sp >= 3) sp -= 3;         // slot for tile t+2
        const int k2 = (t + 2) << 5;
        const bool pf = (t + 2) < nt;
        short8 af[4], bfv[4];

        // ---- phase 0 (M-half 0): read A-half frags + all B frags ----
        #pragma unroll
        for (int i = 0; i < 4; ++i) {
            int ra = wm * 128 + i * 16 + fm;
            af[i] = *(const short8*)(&As[cur][ra * 32 + ((fq ^ ((ra >> 1) & 3)) << 3)]);
        }
        #pragma unroll
        for (int j = 0; j < 4; ++j) {
            int rb = wn * 64 + j * 16 + fm;
            bfv[j] = *(const short8*)(&Bs[cur][rb * 32 + ((fq ^ ((rb >> 1) & 3)) << 3)]);
        }
        if (pf) { async16(a0 + k2, &As[sp][ld0]); async16(a1 + k2, &As[sp][ld1]); }
        __builtin_amdgcn_s_barrier();
        __builtin_amdgcn_s_setprio(1);
        #pragma unroll
        for (int i = 0; i < 4; ++i)
            #pragma unroll
            for (int j = 0; j < 4; ++j)
                acc[i][j] = __builtin_amdgcn_mfma_f32_16x16x32_bf16(
                    af[i], bfv[j], acc[i][j], 0, 0, 0);
        __builtin_amdgcn_s_setprio(0);
        __builtin_amdgcn_s_barrier();

        // ---- phase 1 (M-half 1): reuse bfv ----
        #pragma unroll
        for (int i = 0; i < 4; ++i) {
            int ra = wm * 128 + 64 + i * 16 + fm;
            af[i] = *(const short8*)(&As[cur][ra * 32 + ((fq ^ ((ra >> 1) & 3)) << 3)]);
        }
        if (pf) { async16(b0 + k2, &Bs[sp][ld0]); async16(b1 + k2, &Bs[sp][ld1]); }
        if (t + 1 < nt) {
            // guard tile t+1 landed before next iteration's reads:
            // outstanding after this phase's stage = tile t+2's 4 (if staged)
            if (pf) asm volatile("s_waitcnt vmcnt(4)" ::: "memory");
            else    asm volatile("s_waitcnt vmcnt(0)" ::: "memory");
        }
        __builtin_amdgcn_s_barrier();
        __builtin_amdgcn_s_setprio(1);
        #pragma unroll
        for (int i = 0; i < 4; ++i)
            #pragma unroll
            for (int j = 0; j < 4; ++j)
                acc[4 + i][j] = __builtin_amdgcn_mfma_f32_16x16x32_bf16(
                    af[i], bfv[j], acc[4 + i][j], 0, 0, 0);
        __builtin_amdgcn_s_setprio(0);
        __builtin_amdgcn_s_barrier();

        ++cur; if (cur >= 3) cur = 0;
    }

    // epilogue: per-wave 128x64 block
    #pragma unroll
    for (int ig = 0; ig < 8; ++ig) {
        #pragma unroll
        for (int rr = 0; rr < 4; ++rr) {
            int gm = bm + wm * 128 + ig * 16 + fq * 4 + rr;
            if (gm >= M) continue;
            #pragma unroll
            for (int j = 0; j < 4; ++j) {
                int gn = bn + wn * 64 + j * 16 + fm;
                float v = acc[ig][j][rr];
                if (DO_BIAS) v += bias[gn];
                if (DO_RELU) v = fmaxf(v, 0.0f);
                C[(size_t)gm * Nc + gn] = (bf16)v;
            }
        }
    }
}

// ---------------------------------------------------------------- driver

static inline int cdiv(long long a, int b) { return (int)((a + b - 1) / b); }

extern "C" void kernel_launch(void* const* d_in, const int* in_sizes, int n_in,
                              void* d_out, int out_size, void* d_ws, size_t ws_size,
                              hipStream_t stream) {
    const int N = in_sizes[0] / 3;
    const int E = in_sizes[1] / 2;

    const int* edge_index = (const int*)d_in[1];
    const int* row = edge_index;       // sources
    const int* col = edge_index + E;   // destinations

    char* p = (char*)d_ws;
    auto alloc = [&](size_t bytes) {
        void* r = (void*)p;
        p += (bytes + 255) & ~(size_t)255;
        return r;
    };
    void* bufA    = alloc((size_t)N * 2048);
    void* bufB    = alloc((size_t)N * 1024);
    float* dis    = (float*)alloc((size_t)N * sizeof(float));
    int* offsets  = (int*)alloc((size_t)(N + 1) * sizeof(int));
    int* cursor   = (int*)alloc((size_t)N * sizeof(int));
    int2* csr_sw  = (int2*)alloc((size_t)E * sizeof(int2));
    int* flag     = (int*)alloc(256);
    int* blocksums = (int*)alloc((size_t)cdiv(N, 1024) * sizeof(int));
    const int WfL[5] = {0, 1, 2, 3, 7};
    float* Wf[8] = {};
    float* bf_[8];
    for (int t = 0; t < 5; ++t) {
        int L = WfL[t];
        Wf[L] = (float*)alloc((size_t)in_sizes[2 + 2 * L] * sizeof(float));
    }
    for (int L = 0; L < 8; ++L)
        bf_[L] = (float*)alloc((size_t)in_sizes[3 + 2 * L] * sizeof(float));
    bf16* Wt4 = (bf16*)alloc((size_t)128 * 1024 * sizeof(bf16));
    bf16* Wt5 = (bf16*)alloc((size_t)1024 * 512 * sizeof(bf16));
    bf16* Wt6 = (bf16*)alloc((size_t)512 * 256 * sizeof(bf16));
    size_t needed = (size_t)(p - (char*)d_ws);
    if (ws_size < needed) return;

    float* fA = (float*)bufA;  bf16* hA = (bf16*)bufA;
    float* fB = (float*)bufB;  bf16* hB = (bf16*)bufB;

    const int T = 256;

    // ---- dtype detect ----
    detect_dtype_kernel<<<1, 256, 0, stream>>>((const unsigned short*)d_in[0], flag);

    // ---- fused fp32 converts ----
    {
        CvtJobs cj{};
        int idx = 0, cum = 0;
        auto add = [&](const void* s, float* d, int n) {
            cj.src[idx] = s; cj.dst[idx] = d; cj.off[idx] = cum; cum += n; ++idx;
        };
        add(d_in[0], fA, N * 3);
        for (int t = 0; t < 5; ++t) {
            int L = WfL[t];
            add(d_in[2 + 2 * L], Wf[L], in_sizes[2 + 2 * L]);
        }
        for (int L = 0; L < 8; ++L)
            add(d_in[3 + 2 * L], bf_[L], in_sizes[3 + 2 * L]);
        cj.off[idx] = cum; cj.cnt = idx;
        cvt_fused_kernel<<<cdiv(cum, T), T, 0, stream>>>(cj, flag);
    }

    // ---- fused bf16 weight transposes ----
    {
        WtJobs wj{};
        wj.src[0] = d_in[2 + 2 * 4]; wj.dst[0] = Wt4; wj.K[0] = 128;  wj.N[0] = 1024;
        wj.src[1] = d_in[2 + 2 * 5]; wj.dst[1] = Wt5; wj.K[1] = 1024; wj.N[1] = 512;
        wj.src[2] = d_in[2 + 2 * 6]; wj.dst[2] = Wt6; wj.K[2] = 512;  wj.N[2] = 256;
        wj.off[0] = 0;
        wj.off[1] = 128 * 1024;
        wj.off[2] = 128 * 1024 + 1024 * 512;
        wj.off[3] = 128 * 1024 + 1024 * 512 + 512 * 256;
        wt_fused_kernel<<<cdiv(wj.off[3], T), T, 0, stream>>>(wj, flag);
    }

    // ---- CSR build ----
    {
        zero_int_kernel<<<cdiv(N, T), T, 0, stream>>>(cursor, N);
        hist_kernel<<<cdiv(E, T), T, 0, stream>>>(col, cursor, E);
        int nb = cdiv(N, 1024);
        scan_reduce_kernel<<<nb, 1024, 0, stream>>>(cursor, blocksums, N);
        scan_blocksums_kernel<<<1, 1024, 0, stream>>>(blocksums, nb);
        scan_final_kernel<<<nb, 1024, 0, stream>>>(cursor, blocksums, offsets, dis, N);
        fill_kernel<<<cdiv(E, T), T, 0, stream>>>(row, col, offsets, cursor, csr_sw, dis, E);
    }

    // L0: 3->64 aggFirst
    agg_kernel<float, float><<<cdiv((long long)N * 3, T), T, 0, stream>>>(
        fA, offsets, csr_sw, dis, nullptr, fB, N, 3, 0, 0);
    gemm_k3_kernel<<<cdiv((long long)N * 16, T), T, 0, stream>>>(fB, Wf[0], bf_[0], fA, N);

    // L1: 64->64 gemmFirst
    {
        dim3 g(cdiv(N, 64), 1);
        gemm_k64_kernel<float><<<g, 256, 0, stream>>>(fA, Wf[1], nullptr, fB, N, 64, 0, 0);
        agg_vec_kernel<64, 1, 1, float, float><<<cdiv((long long)N * 16, T), T, 0, stream>>>(
            fB, offsets, csr_sw, dis, bf_[1], fA, N);
    }

    // L2: 64->64 same
    {
        dim3 g(cdiv(N, 64), 1);
        gemm_k64_kernel<float><<<g, 256, 0, stream>>>(fA, Wf[2], nullptr, fB, N, 64, 0, 0);
        agg_vec_kernel<64, 1, 1, float, float><<<cdiv((long long)N * 16, T), T, 0, stream>>>(
            fB, offsets, csr_sw, dis, bf_[2], fA, N);
    }

    // L3: 64->128 aggFirst
    {
        agg_vec_kernel<64, 0, 0, float, float><<<cdiv((long long)N * 16, T), T, 0, stream>>>(
            fA, offsets, csr_sw, dis, nullptr, fB, N);
        dim3 g(cdiv(N, 64), 2);
        gemm_k64_kernel<bf16><<<g, 256, 0, stream>>>(fB, Wf[3], bf_[3], hA, N, 128, 1, 1);
    }

    // L4: 128->1024 aggFirst: agg_vec -> hB, single-shot MFMA -> hA
    {
        agg_vec_kernel<128, 0, 0, bf16, bf16><<<cdiv((long long)N * 16, T), T, 0, stream>>>(
            hA, offsets, csr_sw, dis, nullptr, hB, N);
        int nwg = cdiv(N, 128) * (1024 / 128);
        gemm_mfma_k128_kernel<1, 1><<<nwg, 256, 0, stream>>>(hB, Wt4, bf_[4], hA, N, 1024);
    }

    // L5: 1024->512 gemmFirst: 256x256 phased MFMA -> hB, agg_vec -> hA
    {
        int nwg = cdiv(N, 256) * (512 / 256);
        gemm_mfma_256_kernel<0, 0><<<nwg, 512, 0, stream>>>(hA, Wt5, nullptr, hB, N, 512, 1024);
        agg_vec_kernel<512, 1, 1, bf16, bf16><<<cdiv((long long)N * 64, T), T, 0, stream>>>(
            hB, offsets, csr_sw, dis, bf_[5], hA, N);
    }

    // L6: 512->256 gemmFirst: 256x256 phased MFMA -> hB, agg_vec -> hA
    {
        int nwg = cdiv(N, 256) * (256 / 256);
        gemm_mfma_256_kernel<0, 0><<<nwg, 512, 0, stream>>>(hA, Wt6, nullptr, hB, N, 256, 512);
        agg_vec_kernel<256, 1, 1, bf16, bf16><<<cdiv((long long)N * 32, T), T, 0, stream>>>(
            hB, offsets, csr_sw, dis, bf_[6], hA, N);
    }

    // L7: 256->2 gemmFirst: vectorized f2 GEMM -> fB, fused agg+out -> d_out
    {
        gemm_f2_kernel<<<cdiv(N, T), T, 0, stream>>>(hA, Wf[7], fB, N);
        agg2_out_kernel<<<cdiv((long long)N * 2, T), T, 0, stream>>>(
            fB, offsets, csr_sw, dis, bf_[7], d_out, N, flag);
    }
}